// Round 9
// baseline (259.876 us; speedup 1.0000x reference)
//
#include <hip/hip_runtime.h>
#include <math.h>

#define Bn 4
#define Cn 32
#define Dn 64
#define Hn 64
#define Wn 64
#define DHW (Dn * Hn * Wn)      /* 262144 */
#define TOT (Bn * Cn * DHW)     /* 33554432 */
#define NCHUNK 128              /* spatial chunks per batch in reduce */

typedef float f4 __attribute__((ext_vector_type(4)));

// ============================================================
// Kernel 1: fused reductions (atomic-free, fence-free).
// 512 blocks; each covers 2048 consecutive spatial x 32 channels.
// (R7 lesson: no __threadfence — device-scope fences are per-block L2 ops.)
// ============================================================
__global__ __launch_bounds__(256) void reduce_kernel(
    const float* __restrict__ x,
    float* __restrict__ s_avg, float* __restrict__ s_max,
    float* __restrict__ part_sum, float* __restrict__ part_max) {
    const int b = blockIdx.x / NCHUNK;
    const int chunk = blockIdx.x % NCHUNK;
    const int base = chunk * 2048 + threadIdx.x * 4;
    const int lane = threadIdx.x & 63;
    const int wid = threadIdx.x >> 6;

    f4 ssum0 = {0.f, 0.f, 0.f, 0.f}, ssum1 = {0.f, 0.f, 0.f, 0.f};
    f4 smax0 = {-INFINITY, -INFINITY, -INFINITY, -INFINITY};
    f4 smax1 = smax0;
    float tsum[Cn], tmax[Cn];

    const float* xp = x + (size_t)b * Cn * DHW + base;
#pragma unroll
    for (int c = 0; c < Cn; ++c) {
        const f4 v0 = *reinterpret_cast<const f4*>(xp + (size_t)c * DHW);
        const f4 v1 = *reinterpret_cast<const f4*>(xp + (size_t)c * DHW + 1024);
        ssum0 += v0; ssum1 += v1;
        smax0.x = fmaxf(smax0.x, v0.x); smax0.y = fmaxf(smax0.y, v0.y);
        smax0.z = fmaxf(smax0.z, v0.z); smax0.w = fmaxf(smax0.w, v0.w);
        smax1.x = fmaxf(smax1.x, v1.x); smax1.y = fmaxf(smax1.y, v1.y);
        smax1.z = fmaxf(smax1.z, v1.z); smax1.w = fmaxf(smax1.w, v1.w);
        const float s0 = (v0.x + v0.y) + (v0.z + v0.w);
        const float s1 = (v1.x + v1.y) + (v1.z + v1.w);
        tsum[c] = s0 + s1;
        const float m0 = fmaxf(fmaxf(v0.x, v0.y), fmaxf(v0.z, v0.w));
        const float m1 = fmaxf(fmaxf(v1.x, v1.y), fmaxf(v1.z, v1.w));
        tmax[c] = fmaxf(m0, m1);
    }

    float* avp = s_avg + (size_t)b * DHW + base;
    float* mxp = s_max + (size_t)b * DHW + base;
    *reinterpret_cast<f4*>(avp) = ssum0 * (1.f / Cn);
    *reinterpret_cast<f4*>(avp + 1024) = ssum1 * (1.f / Cn);
    *reinterpret_cast<f4*>(mxp) = smax0;
    *reinterpret_cast<f4*>(mxp + 1024) = smax1;

    __shared__ float redS[4][Cn];
    __shared__ float redM[4][Cn];
#pragma unroll
    for (int c = 0; c < Cn; ++c) {
        float ps = tsum[c], pm = tmax[c];
#pragma unroll
        for (int off = 32; off; off >>= 1) {
            ps += __shfl_xor(ps, off);
            pm = fmaxf(pm, __shfl_xor(pm, off));
        }
        if (lane == 0) { redS[wid][c] = ps; redM[wid][c] = pm; }
    }
    __syncthreads();
    if (threadIdx.x < Cn) {
        const int c = threadIdx.x;
        float s = (redS[0][c] + redS[1][c]) + (redS[2][c] + redS[3][c]);
        float m = fmaxf(fmaxf(redM[0][c], redM[1][c]),
                        fmaxf(redM[2][c], redM[3][c]));
        part_sum[(b * Cn + c) * NCHUNK + chunk] = s;
        part_max[(b * Cn + c) * NCHUNK + chunk] = m;
    }
}

// ============================================================
// Kernel 2: partial-reduce + channel-attention MLP. 1 block, 256 threads.
// ============================================================
__global__ __launch_bounds__(256) void ca_kernel(
    const float* __restrict__ part_sum, const float* __restrict__ part_max,
    const float* __restrict__ fc1_w, const float* __restrict__ fc1_b,
    const float* __restrict__ fc2_w, const float* __restrict__ fc2_b,
    float* __restrict__ ca) {
    __shared__ float inpAll[Bn][64];
    __shared__ float h[128];
    const int t = threadIdx.x;
    {
        const int which = t >> 7;        // 0: sum, 1: max
        const int b = (t >> 5) & 3;
        const int c = t & 31;
        const f4* p4 = reinterpret_cast<const f4*>(
            (which ? part_max : part_sum) + (b * Cn + c) * NCHUNK);
        if (which == 0) {
            float acc = 0.f;
#pragma unroll
            for (int i = 0; i < NCHUNK / 4; ++i) {
                f4 v = p4[i];
                acc += (v.x + v.y) + (v.z + v.w);
            }
            inpAll[b][c] = acc * (1.f / DHW);
        } else {
            float m = -INFINITY;
#pragma unroll
            for (int i = 0; i < NCHUNK / 4; ++i) {
                f4 v = p4[i];
                m = fmaxf(m, fmaxf(fmaxf(v.x, v.y), fmaxf(v.z, v.w)));
            }
            inpAll[b][Cn + c] = m;
        }
    }
    __syncthreads();
#pragma unroll 1
    for (int b = 0; b < Bn; ++b) {
        if (t < 128) {
            float acc = fc1_b[t];
#pragma unroll
            for (int k = 0; k < 64; ++k) acc += fc1_w[t * 64 + k] * inpAll[b][k];
            h[t] = fmaxf(acc, 0.f);
        }
        __syncthreads();
        if (t < Cn) {
            float a2 = fc2_b[t];
#pragma unroll
            for (int k = 0; k < 128; ++k) a2 += fc2_w[t * 128 + k] * h[k];
            ca[b * Cn + t] = 1.f / (1.f + expf(-a2));
        }
        __syncthreads();
    }
}

// ============================================================
// Kernel 3: conv + epilogue, SOFTWARE-PIPELINED across z-steps.
// 256 blocks = 1/CU, each owns (b, y-tile of 4, z-quarter of 16) = 4 steps
// of 4 z. Double-buffered halo (2 x 56 KB). Per step:
//   compute(bufA) -> stage bufB (its vmcnt waits only see LAST step's
//   stores, which had a full compute to drain) -> sigmoid -> fire NT
//   stores from registers -> raw s_barrier with lgkmcnt(0) ONLY.
// KEY: no __syncthreads in the loop -> no vmcnt(0) drain -> stores stay
// in flight under the next step's compute (T3/T4 pattern).
// ============================================================
#define TZs 4
#define NSTEP 4
#define TYc 4
#define LXc (Wn + 6)   /* 70 */
#define LYc (TYc + 6)  /* 10 */
#define LZs (TZs + 6)  /* 10 */
#define HALO1 (LZs * LYc * LXc)  /* 7000 */
#define HALOB (2 * HALO1)        /* 14000 floats = 56 KB */

__device__ __forceinline__ void stage_halo(
    float* __restrict__ dst, const float* __restrict__ srcA,
    const float* __restrict__ srcM, int zstart, int ystart, int t) {
    for (int i = t; i < HALOB; i += 256) {
        const int ic = i / HALO1;
        const int r0 = i - ic * HALO1;
        const int zz = r0 / (LYc * LXc);
        const int r1 = r0 - zz * (LYc * LXc);
        const int yy = r1 / LXc;
        const int xx = r1 - yy * LXc;
        const int gz = zstart + zz, gy = ystart + yy, gx = xx - 3;
        float v = 0.f;
        if ((unsigned)gz < (unsigned)Dn && (unsigned)gy < (unsigned)Hn &&
            (unsigned)gx < (unsigned)Wn)
            v = (ic ? srcM : srcA)[(gz * Hn + gy) * Wn + gx];
        dst[i] = v;
    }
}

__global__ __launch_bounds__(256) void conv_kernel(
    const float* __restrict__ ca_g,
    const float* __restrict__ s_avg, const float* __restrict__ s_max,
    const float* __restrict__ w1, const float* __restrict__ w2,
    float* __restrict__ out) {
    __shared__ float sIn[2][HALOB];   // 112 KB
    __shared__ float ca_s[Cn];

    const int t = threadIdx.x;
    const int bid = blockIdx.x;
    const int b = bid >> 6;             // 64 tiles per batch
    const int ty = (bid >> 2) & 15;
    const int zq = bid & 3;
    const int y0 = ty * TYc;
    const int zbase = zq * (TZs * NSTEP);

    if (t < Cn) ca_s[t] = ca_g[b * Cn + t];

    const float* srcA = s_avg + (size_t)b * DHW;
    const float* srcM = s_max + (size_t)b * DHW;

    // prologue: stage step 0
    stage_halo(sIn[0], srcA, srcM, zbase - 3, y0 - 3, t);
    asm volatile("s_waitcnt lgkmcnt(0)" ::: "memory");
    __builtin_amdgcn_s_barrier();
    __builtin_amdgcn_sched_barrier(0);

    const int lx = t & 63, ly = t >> 6;
    const float c20 = w2[0], c21 = w2[1], c22 = w2[2], c23 = w2[3];

#pragma unroll 1
    for (int step = 0; step < NSTEP; ++step) {
        const int cur = step & 1;
        const float* buf = sIn[cur];

        // ---- compute this step's 4x4 (oc x oz) accumulators ----
        float acc[4][TZs];
#pragma unroll
        for (int oc = 0; oc < 4; ++oc)
#pragma unroll
            for (int o = 0; o < TZs; ++o) acc[oc][o] = 0.f;

#pragma unroll 1
        for (int ic = 0; ic < 2; ++ic)
#pragma unroll 1
            for (int kh = 0; kh < 7; ++kh)
#pragma unroll 1
                for (int kw = 0; kw < 7; ++kw) {
                    float incol[LZs];
#pragma unroll
                    for (int s = 0; s < LZs; ++s)
                        incol[s] = buf[ic * HALO1 +
                                       (s * LYc + (ly + kh)) * LXc + (lx + kw)];
#pragma unroll
                    for (int kd = 0; kd < 7; ++kd)
#pragma unroll
                        for (int oc = 0; oc < 4; ++oc) {
                            // wave-uniform address -> scalar load
                            float w =
                                w1[(((oc * 2 + ic) * 7 + kd) * 7 + kh) * 7 + kw];
#pragma unroll
                            for (int o = 0; o < TZs; ++o)
                                acc[oc][o] += incol[o + kd] * w;
                        }
                }

        // ---- stage next step into the other buffer ----
        if (step < NSTEP - 1)
            stage_halo(sIn[cur ^ 1], srcA, srcM,
                       zbase + (step + 1) * TZs - 3, y0 - 3, t);
        __builtin_amdgcn_sched_barrier(0);  // keep stores AFTER stage loads

        // ---- sigmoid + fire NT stores straight from registers ----
        float sv[TZs];
#pragma unroll
        for (int o = 0; o < TZs; ++o) {
            float s = fmaxf(acc[0][o], 0.f) * c20 +
                      fmaxf(acc[1][o], 0.f) * c21 +
                      fmaxf(acc[2][o], 0.f) * c22 +
                      fmaxf(acc[3][o], 0.f) * c23;
            sv[o] = 1.f / (1.f + expf(-s));
        }
        const size_t base = (size_t)b * Cn * DHW +
                            (size_t)(zbase + step * TZs) * (Hn * Wn) +
                            (size_t)(y0 + ly) * Wn + lx;
#pragma unroll 1
        for (int c = 0; c < Cn; ++c) {
            const float cav = ca_s[c];
            const size_t cb = base + (size_t)c * DHW;
#pragma unroll
            for (int o = 0; o < TZs; ++o) {
                const float a = sv[o] * cav;
                __builtin_nontemporal_store(a, out + cb + o * (Hn * Wn));
                __builtin_nontemporal_store(1.f - a,
                                            out + TOT + cb + o * (Hn * Wn));
            }
        }

        // ---- raw barrier: wave sync + LDS drain, NO vmcnt(0) drain ----
        asm volatile("s_waitcnt lgkmcnt(0)" ::: "memory");
        __builtin_amdgcn_s_barrier();
        __builtin_amdgcn_sched_barrier(0);
    }
}

extern "C" void kernel_launch(void* const* d_in, const int* in_sizes, int n_in,
                              void* d_out, int out_size, void* d_ws,
                              size_t ws_size, hipStream_t stream) {
    const float* x = (const float*)d_in[0];
    const float* fc1_w = (const float*)d_in[1];
    const float* fc1_b = (const float*)d_in[2];
    const float* fc2_w = (const float*)d_in[3];
    const float* fc2_b = (const float*)d_in[4];
    const float* conv1_w = (const float*)d_in[5];
    const float* conv2_w = (const float*)d_in[6];

    float* ws = (float*)d_ws;
    float* s_avg = ws;                               // B*DHW
    float* s_max = s_avg + (size_t)Bn * DHW;         // B*DHW
    float* part_sum = s_max + (size_t)Bn * DHW;      // B*C*NCHUNK
    float* part_max = part_sum + Bn * Cn * NCHUNK;   // B*C*NCHUNK
    float* ca = part_max + Bn * Cn * NCHUNK;         // B*C

    reduce_kernel<<<Bn * NCHUNK, 256, 0, stream>>>(x, s_avg, s_max, part_sum,
                                                   part_max);
    ca_kernel<<<1, 256, 0, stream>>>(part_sum, part_max, fc1_w, fc1_b, fc2_w,
                                     fc2_b, ca);
    conv_kernel<<<Bn * 64, 256, 0, stream>>>(ca, s_avg, s_max, conv1_w,
                                             conv2_w, (float*)d_out);
}

// Round 10
// 223.080 us; speedup vs baseline: 1.1649x; 1.1649x over previous
//
#include <hip/hip_runtime.h>
#include <math.h>

#define Bn 4
#define Cn 32
#define Dn 64
#define Hn 64
#define Wn 64
#define DHW (Dn * Hn * Wn)      /* 262144 */
#define TOT (Bn * Cn * DHW)     /* 33554432 */
#define NCHUNK 256              /* spatial chunks per batch in reduce */

typedef float f4 __attribute__((ext_vector_type(4)));

// ============================================================
// Kernel 1: fused reductions (atomic-free, fence-free).
// 1024 blocks (4/CU); channel loop batched 8-wide so 8 independent f4
// loads are in flight per wave (R9 lesson: ILP was ~5 loads -> 3.3 TB/s).
// __launch_bounds__(256,4): cap VGPR <=128 so 4 blocks/CU stay resident.
// ============================================================
__global__ __launch_bounds__(256, 4) void reduce_kernel(
    const float* __restrict__ x,
    float* __restrict__ s_avg, float* __restrict__ s_max,
    float* __restrict__ part_sum, float* __restrict__ part_max) {
    const int b = blockIdx.x / NCHUNK;
    const int chunk = blockIdx.x % NCHUNK;
    const int base = chunk * 1024 + threadIdx.x * 4;
    const int lane = threadIdx.x & 63;
    const int wid = threadIdx.x >> 6;

    f4 ssum = {0.f, 0.f, 0.f, 0.f};
    f4 smax = {-INFINITY, -INFINITY, -INFINITY, -INFINITY};
    float tsum[Cn], tmax[Cn];

    const float* xp = x + (size_t)b * Cn * DHW + base;
#pragma unroll
    for (int g = 0; g < Cn / 8; ++g) {
        f4 v[8];
#pragma unroll
        for (int j = 0; j < 8; ++j)
            v[j] = *reinterpret_cast<const f4*>(xp + (size_t)(g * 8 + j) * DHW);
#pragma unroll
        for (int j = 0; j < 8; ++j) {
            const int c = g * 8 + j;
            ssum += v[j];
            smax.x = fmaxf(smax.x, v[j].x); smax.y = fmaxf(smax.y, v[j].y);
            smax.z = fmaxf(smax.z, v[j].z); smax.w = fmaxf(smax.w, v[j].w);
            tsum[c] = (v[j].x + v[j].y) + (v[j].z + v[j].w);
            tmax[c] = fmaxf(fmaxf(v[j].x, v[j].y), fmaxf(v[j].z, v[j].w));
        }
    }

    *reinterpret_cast<f4*>(s_avg + (size_t)b * DHW + base) = ssum * (1.f / Cn);
    *reinterpret_cast<f4*>(s_max + (size_t)b * DHW + base) = smax;

    __shared__ float redS[4][Cn];
    __shared__ float redM[4][Cn];
#pragma unroll
    for (int c = 0; c < Cn; ++c) {
        float ps = tsum[c], pm = tmax[c];
#pragma unroll
        for (int off = 32; off; off >>= 1) {
            ps += __shfl_xor(ps, off);
            pm = fmaxf(pm, __shfl_xor(pm, off));
        }
        if (lane == 0) { redS[wid][c] = ps; redM[wid][c] = pm; }
    }
    __syncthreads();
    if (threadIdx.x < Cn) {
        const int c = threadIdx.x;
        float s = (redS[0][c] + redS[1][c]) + (redS[2][c] + redS[3][c]);
        float m = fmaxf(fmaxf(redM[0][c], redM[1][c]),
                        fmaxf(redM[2][c], redM[3][c]));
        part_sum[(b * Cn + c) * NCHUNK + chunk] = s;
        part_max[(b * Cn + c) * NCHUNK + chunk] = m;
    }
}

// ============================================================
// Kernel 2: partial-reduce + channel-attention MLP. 1 block, 256 threads.
// ============================================================
__global__ __launch_bounds__(256) void ca_kernel(
    const float* __restrict__ part_sum, const float* __restrict__ part_max,
    const float* __restrict__ fc1_w, const float* __restrict__ fc1_b,
    const float* __restrict__ fc2_w, const float* __restrict__ fc2_b,
    float* __restrict__ ca) {
    __shared__ float inpAll[Bn][64];
    __shared__ float h[128];
    const int t = threadIdx.x;
    {
        const int which = t >> 7;        // 0: sum, 1: max
        const int b = (t >> 5) & 3;
        const int c = t & 31;
        const f4* p4 = reinterpret_cast<const f4*>(
            (which ? part_max : part_sum) + (b * Cn + c) * NCHUNK);
        if (which == 0) {
            float acc = 0.f;
#pragma unroll
            for (int i = 0; i < NCHUNK / 4; ++i) {
                f4 v = p4[i];
                acc += (v.x + v.y) + (v.z + v.w);
            }
            inpAll[b][c] = acc * (1.f / DHW);
        } else {
            float m = -INFINITY;
#pragma unroll
            for (int i = 0; i < NCHUNK / 4; ++i) {
                f4 v = p4[i];
                m = fmaxf(m, fmaxf(fmaxf(v.x, v.y), fmaxf(v.z, v.w)));
            }
            inpAll[b][Cn + c] = m;
        }
    }
    __syncthreads();
#pragma unroll 1
    for (int b = 0; b < Bn; ++b) {
        if (t < 128) {
            float acc = fc1_b[t];
#pragma unroll
            for (int k = 0; k < 64; ++k) acc += fc1_w[t * 64 + k] * inpAll[b][k];
            h[t] = fmaxf(acc, 0.f);
        }
        __syncthreads();
        if (t < Cn) {
            float a2 = fc2_b[t];
#pragma unroll
            for (int k = 0; k < 128; ++k) a2 += fc2_w[t * 128 + k] * h[k];
            ca[b * Cn + t] = 1.f / (1.f + expf(-a2));
        }
        __syncthreads();
    }
}

// ============================================================
// Kernel 3: conv + epilogue (R6 structure, smaller tile for occupancy).
//  Tile 64x * 2y * 4z; both ic halos in LDS = 44.8 KB -> 3 blocks/CU.
//  2048 blocks = ~8 scheduling rounds/CU -> natural compute/store overlap
//  (R9 lesson: occupancy beats hand pipelining here).
//  Stores: straight from registers, NT, 256B contiguous per wave-inst.
// ============================================================
#define TZc 4
#define TYc 2
#define LXc (Wn + 6)   /* 70 */
#define LYc (TYc + 6)  /* 8  */
#define LZc (TZc + 6)  /* 10 */
#define HALO1 (LZc * LYc * LXc)  /* 5600 */

__global__ __launch_bounds__(256) void conv_kernel(
    const float* __restrict__ ca_g,
    const float* __restrict__ s_avg, const float* __restrict__ s_max,
    const float* __restrict__ w1, const float* __restrict__ w2,
    float* __restrict__ out) {
    __shared__ float sIn[2 * HALO1];          // 44.8 KB
    __shared__ float ca_s[Cn];

    const int t = threadIdx.x;
    const int bid = blockIdx.x;
    const int b = bid >> 9;            // 512 tiles per batch
    const int tile = bid & 511;
    const int tz = tile >> 5, ty = tile & 31;  // 16 z-tiles x 32 y-tiles
    const int z0 = tz * TZc, y0 = ty * TYc;

    if (t < Cn) ca_s[t] = ca_g[b * Cn + t];

    // ---- load both halo buffers ----
    const float* srcA = s_avg + (size_t)b * DHW;
    const float* srcM = s_max + (size_t)b * DHW;
    for (int i = t; i < 2 * HALO1; i += 256) {
        const int ic = i / HALO1;
        const int r0 = i - ic * HALO1;
        const int xx = r0 % LXc;
        const int rem = r0 / LXc;
        const int yy = rem % LYc;
        const int zz = rem / LYc;
        const int gz = z0 + zz - 3, gy = y0 + yy - 3, gx = xx - 3;
        float v = 0.f;
        if ((unsigned)gz < (unsigned)Dn && (unsigned)gy < (unsigned)Hn &&
            (unsigned)gx < (unsigned)Wn)
            v = (ic ? srcM : srcA)[(gz * Hn + gy) * Wn + gx];
        sIn[i] = v;
    }
    __syncthreads();

    // ---- compute: thread (lx, ly, zh) owns 2 z outputs ----
    const int lx = t & 63, ly = (t >> 6) & 1, zh = t >> 7;

    float acc[4][2];  // [oc][o]
#pragma unroll
    for (int oc = 0; oc < 4; ++oc)
#pragma unroll
        for (int o = 0; o < 2; ++o) acc[oc][o] = 0.f;

#pragma unroll 1
    for (int ic = 0; ic < 2; ++ic)
#pragma unroll 1
        for (int kh = 0; kh < 7; ++kh)
#pragma unroll 1
            for (int kw = 0; kw < 7; ++kw) {
                float incol[8];
#pragma unroll
                for (int s = 0; s < 8; ++s)
                    incol[s] = sIn[ic * HALO1 +
                                   ((zh * 2 + s) * LYc + (ly + kh)) * LXc +
                                   (lx + kw)];
#pragma unroll
                for (int kd = 0; kd < 7; ++kd)
#pragma unroll
                    for (int oc = 0; oc < 4; ++oc) {
                        // wave-uniform address -> scalar load
                        float w = w1[(((oc * 2 + ic) * 7 + kd) * 7 + kh) * 7 + kw];
#pragma unroll
                        for (int o = 0; o < 2; ++o)
                            acc[oc][o] += incol[o + kd] * w;
                    }
            }

    const float c20 = w2[0], c21 = w2[1], c22 = w2[2], c23 = w2[3];
    float sv[2];
#pragma unroll
    for (int o = 0; o < 2; ++o) {
        float s = fmaxf(acc[0][o], 0.f) * c20 + fmaxf(acc[1][o], 0.f) * c21 +
                  fmaxf(acc[2][o], 0.f) * c22 + fmaxf(acc[3][o], 0.f) * c23;
        sv[o] = 1.f / (1.f + expf(-s));
    }

    // ---- NT stores from registers; 256B contiguous per wave-inst ----
    const size_t base = (size_t)b * Cn * DHW +
                        (size_t)(z0 + zh * 2) * (Hn * Wn) +
                        (size_t)(y0 + ly) * Wn + lx;
#pragma unroll 1
    for (int c = 0; c < Cn; ++c) {
        const float cav = ca_s[c];
        const size_t cb = base + (size_t)c * DHW;
#pragma unroll
        for (int o = 0; o < 2; ++o) {
            const float a = sv[o] * cav;
            __builtin_nontemporal_store(a, out + cb + o * (Hn * Wn));
            __builtin_nontemporal_store(1.f - a, out + TOT + cb + o * (Hn * Wn));
        }
    }
}

extern "C" void kernel_launch(void* const* d_in, const int* in_sizes, int n_in,
                              void* d_out, int out_size, void* d_ws,
                              size_t ws_size, hipStream_t stream) {
    const float* x = (const float*)d_in[0];
    const float* fc1_w = (const float*)d_in[1];
    const float* fc1_b = (const float*)d_in[2];
    const float* fc2_w = (const float*)d_in[3];
    const float* fc2_b = (const float*)d_in[4];
    const float* conv1_w = (const float*)d_in[5];
    const float* conv2_w = (const float*)d_in[6];

    float* ws = (float*)d_ws;
    float* s_avg = ws;                               // B*DHW
    float* s_max = s_avg + (size_t)Bn * DHW;         // B*DHW
    float* part_sum = s_max + (size_t)Bn * DHW;      // B*C*NCHUNK
    float* part_max = part_sum + Bn * Cn * NCHUNK;   // B*C*NCHUNK
    float* ca = part_max + Bn * Cn * NCHUNK;         // B*C

    reduce_kernel<<<Bn * NCHUNK, 256, 0, stream>>>(x, s_avg, s_max, part_sum,
                                                   part_max);
    ca_kernel<<<1, 256, 0, stream>>>(part_sum, part_max, fc1_w, fc1_b, fc2_w,
                                     fc2_b, ca);
    conv_kernel<<<Bn * 512, 256, 0, stream>>>(ca, s_avg, s_max, conv1_w,
                                              conv2_w, (float*)d_out);
}